// Round 15
// baseline (416.429 us; speedup 1.0000x reference)
//
#include <hip/hip_runtime.h>
#include <math.h>

#define FIN 256
#define HID 64
#define NC  16

// ================= histogram =================

__global__ void k_hist(const int* __restrict__ row, int* __restrict__ cnt, int E) {
    int e = blockIdx.x * blockDim.x + threadIdx.x;
    if (e < E) atomicAdd(&cnt[row[e]], 1);
}

// ================= exclusive scan of cnt -> off (2-level) =================

__global__ void k_scan_block(const int* __restrict__ cnt, int* __restrict__ offtmp,
                             int* __restrict__ bsum, int N) {
    __shared__ int s[256];
    int t = threadIdx.x, i = blockIdx.x * 256 + t;
    int v = (i < N) ? cnt[i] : 0;
    s[t] = v; __syncthreads();
    for (int d = 1; d < 256; d <<= 1) {
        int add = (t >= d) ? s[t - d] : 0;
        __syncthreads();
        s[t] += add;
        __syncthreads();
    }
    if (i < N) offtmp[i] = s[t] - v;
    if (t == 255) bsum[blockIdx.x] = s[255];
}

__global__ void k_scan_bsum(int* __restrict__ bsum, int nb) {
    __shared__ int s[256];
    int t = threadIdx.x;
    int v = (t < nb) ? bsum[t] : 0;
    s[t] = v; __syncthreads();
    for (int d = 1; d < 256; d <<= 1) {
        int add = (t >= d) ? s[t - d] : 0;
        __syncthreads();
        s[t] += add;
        __syncthreads();
    }
    if (t < nb) bsum[t] = s[t] - v;
}

// off/cur from scan, dinv from cnt (fused, one pass over nodes)
__global__ void k_off(const int* __restrict__ offtmp, const int* __restrict__ bsum,
                      const int* __restrict__ cnt, int* __restrict__ off,
                      int* __restrict__ cur, float* __restrict__ dinv, int N) {
    int i = blockIdx.x * blockDim.x + threadIdx.x;
    if (i < N) {
        int o = offtmp[i] + bsum[i >> 8];
        off[i] = o;
        cur[i] = o;
        dinv[i] = rsqrtf((float)(cnt[i] + 1));   // +1 self loop
    }
}

// bucket start cursors: bucket b covers nodes [b*256, (b+1)*256)
__global__ void k_bstart(const int* __restrict__ off, int* __restrict__ bcur, int NB) {
    int b = threadIdx.x;
    if (b < NB) bcur[b] = off[b << 8];
}

// ================= pass 1: bin edges by bucket into stage =================

#define BIN_CHUNK 4096   // 256 threads x 16 edges

__global__ __launch_bounds__(256) void k_bin(const int* __restrict__ row,
                                             const int* __restrict__ col,
                                             int* __restrict__ bcur,
                                             int2* __restrict__ stage, int E) {
    __shared__ unsigned lcnt[256];
    __shared__ unsigned lpos[256];
    const int tid = threadIdx.x;
    const int base = blockIdx.x * BIN_CHUNK;

    lcnt[tid] = 0;
    __syncthreads();

    int      rr[16];
    unsigned myofs[16];
#pragma unroll
    for (int k = 0; k < 16; ++k) {
        int idx = base + tid + k * 256;
        if (idx < E) {
            int r = row[idx];
            rr[k] = r;
            myofs[k] = atomicAdd(&lcnt[r >> 8], 1u);
        }
    }
    __syncthreads();

    unsigned c = lcnt[tid];
    lpos[tid] = (c > 0) ? (unsigned)atomicAdd(&bcur[tid], (int)c) : 0u;
    __syncthreads();

#pragma unroll
    for (int k = 0; k < 16; ++k) {
        int idx = base + tid + k * 256;
        if (idx < E) {
            int r = rr[k];
            unsigned p = lpos[r >> 8] + myofs[k];
            stage[p] = make_int2(r, col[idx]);
        }
    }
}

// ================= pass 2: place staged edges (bucket-localized) =================

__global__ void k_place(const int2* __restrict__ stage, int* __restrict__ cur,
                        int* __restrict__ colS, int E) {
    int e = blockIdx.x * blockDim.x + threadIdx.x;
    if (e < E) {
        int2 rc = stage[e];
        int p = atomicAdd(&cur[rc.x], 1);
        colS[p] = rc.y;
    }
}

// ================= GEMM1: h1 = x @ W1, 64-row tile, 4x4 register tile =================

#define G1_ROWS 64

__global__ __launch_bounds__(256) void k_gemm1(const float* __restrict__ x,
                                               const float* __restrict__ W1,
                                               float* __restrict__ h1, int N) {
    __shared__ float Ws[FIN][HID];           // 64 KB, [k][c]
    __shared__ float xs[G1_ROWS][FIN + 4];   // 66.6 KB, padded
    const int tid = threadIdx.x;
    const int row0 = blockIdx.x * G1_ROWS;

    // load W1: 4096 float4, 16 per thread
    {
        const float4* W4 = (const float4*)W1;
        float4* Ws4 = (float4*)&Ws[0][0];
#pragma unroll
        for (int i = 0; i < 16; ++i) Ws4[tid + i * 256] = W4[tid + i * 256];
    }
    // load x tile: 64 rows x 64 float4, 16 per thread (row-guarded)
    {
#pragma unroll
        for (int i = 0; i < 16; ++i) {
            int idx = tid + i * 256;
            int r = idx >> 6;
            int q = idx & 63;
            int gr = row0 + r;
            float4 v = make_float4(0.f, 0.f, 0.f, 0.f);
            if (gr < N) v = ((const float4*)(x + (size_t)gr * FIN))[q];
            *(float4*)&xs[r][q * 4] = v;
        }
    }
    __syncthreads();

    const int rg = (tid >> 4) << 2;          // row-group base: 0..60
    const int c0 = (tid & 15) << 2;          // col base: 0..60
    float acc[4][4] = {};

#pragma unroll 4
    for (int k = 0; k < FIN; k += 4) {
        float4 w0 = *(const float4*)&Ws[k + 0][c0];
        float4 w1 = *(const float4*)&Ws[k + 1][c0];
        float4 w2 = *(const float4*)&Ws[k + 2][c0];
        float4 w3 = *(const float4*)&Ws[k + 3][c0];
        float4 xv0 = *(const float4*)&xs[rg + 0][k];
        float4 xv1 = *(const float4*)&xs[rg + 1][k];
        float4 xv2 = *(const float4*)&xs[rg + 2][k];
        float4 xv3 = *(const float4*)&xs[rg + 3][k];
#define G1_ROW(i, xv)                                                        \
        acc[i][0] += xv.x * w0.x + xv.y * w1.x + xv.z * w2.x + xv.w * w3.x;  \
        acc[i][1] += xv.x * w0.y + xv.y * w1.y + xv.z * w2.y + xv.w * w3.y;  \
        acc[i][2] += xv.x * w0.z + xv.y * w1.z + xv.z * w2.z + xv.w * w3.z;  \
        acc[i][3] += xv.x * w0.w + xv.y * w1.w + xv.z * w2.w + xv.w * w3.w;
        G1_ROW(0, xv0) G1_ROW(1, xv1) G1_ROW(2, xv2) G1_ROW(3, xv3)
#undef G1_ROW
    }

#pragma unroll
    for (int i = 0; i < 4; ++i) {
        int gr = row0 + rg + i;
        if (gr < N) {
            float4 v = make_float4(acc[i][0], acc[i][1], acc[i][2], acc[i][3]);
            *(float4*)(h1 + (size_t)gr * HID + c0) = v;
        }
    }
}

// ================= agg1: gather-reduce, wave per node, lane = feature =================

__global__ __launch_bounds__(256) void k_agg1(const int* __restrict__ off,
                                              const int* __restrict__ cnt,
                                              const int* __restrict__ colS,
                                              const float* __restrict__ dinv,
                                              const float* __restrict__ h1,
                                              float* __restrict__ agg1, int N) {
    int i = blockIdx.x * 4 + (threadIdx.x >> 6);
    if (i >= N) return;
    int lane = threadIdx.x & 63;
    int s = off[i], n = cnt[i];
    float di = dinv[i];
    float acc = di * h1[(size_t)i * HID + lane];   // self loop (pre-factored)

    int j = 0;
    for (; j + 4 <= n; j += 4) {
        int   c0 = colS[s + j],     c1 = colS[s + j + 1];
        int   c2 = colS[s + j + 2], c3 = colS[s + j + 3];
        float w0 = dinv[c0], w1 = dinv[c1], w2 = dinv[c2], w3 = dinv[c3];
        acc += h1[(size_t)c0 * HID + lane] * w0;
        acc += h1[(size_t)c1 * HID + lane] * w1;
        acc += h1[(size_t)c2 * HID + lane] * w2;
        acc += h1[(size_t)c3 * HID + lane] * w3;
    }
    for (; j < n; ++j) {
        int c = colS[s + j];
        acc += h1[(size_t)c * HID + lane] * dinv[c];
    }
    agg1[(size_t)i * HID + lane] = di * acc;
}

// ================= GEMM2 fused: h2 = relu(agg1 + b1) @ W2 =================

__global__ __launch_bounds__(256) void k_gemm2(const float* __restrict__ agg1,
                                               const float* __restrict__ b1,
                                               const float* __restrict__ W2,
                                               float* __restrict__ h2) {
    __shared__ float Ws[HID * NC];
    __shared__ float hs[16][HID + 4];
    const int tid = threadIdx.x;

#pragma unroll
    for (int i = 0; i < 4; ++i) Ws[tid + i * 256] = W2[tid + i * 256];

    const int n0 = blockIdx.x * 16;
    {
        float4 v = ((const float4*)(agg1 + (size_t)n0 * HID))[tid];
        int n  = tid >> 4;
        int k0 = (tid & 15) << 2;
        float4 bb = *(const float4*)(b1 + k0);
        v.x = fmaxf(v.x + bb.x, 0.f);
        v.y = fmaxf(v.y + bb.y, 0.f);
        v.z = fmaxf(v.z + bb.z, 0.f);
        v.w = fmaxf(v.w + bb.w, 0.f);
        *(float4*)&hs[n][k0] = v;
    }
    __syncthreads();

    const int n = tid >> 4;
    const int c = tid & 15;
    float acc = 0.f;
#pragma unroll
    for (int k = 0; k < HID; ++k) {
        acc += hs[n][k] * Ws[k * NC + c];
    }
    h2[(size_t)(n0 + n) * NC + c] = acc;
}

// ================= agg2 + bias + log_softmax fused =================
// wave per node: f = lane&15, phase = lane>>4; phase-reduce, then 16-lane softmax.

__global__ __launch_bounds__(256) void k_agg2f(const int* __restrict__ off,
                                               const int* __restrict__ cnt,
                                               const int* __restrict__ colS,
                                               const float* __restrict__ dinv,
                                               const float* __restrict__ h2,
                                               const float* __restrict__ b2,
                                               float* __restrict__ out, int N) {
    int i = blockIdx.x * 4 + (threadIdx.x >> 6);
    if (i >= N) return;
    int lane = threadIdx.x & 63;
    int f = lane & 15;
    int k = lane >> 4;
    int s = off[i], n = cnt[i];

    float acc = 0.f;
    for (int j = k; j < n; j += 4) {
        int c = colS[s + j];
        acc += h2[(size_t)c * NC + f] * dinv[c];
    }
    acc += __shfl_xor(acc, 16, 64);
    acc += __shfl_xor(acc, 32, 64);           // every lane now has S_f for its f

    float di = dinv[i];
    float v = di * (acc + di * h2[(size_t)i * NC + f]) + b2[f];

    // 16-lane softmax reduce (masks 1,2,4,8 stay within each 16-lane group)
    float m = v;
    m = fmaxf(m, __shfl_xor(m, 1, 64));
    m = fmaxf(m, __shfl_xor(m, 2, 64));
    m = fmaxf(m, __shfl_xor(m, 4, 64));
    m = fmaxf(m, __shfl_xor(m, 8, 64));
    float ex = expf(v - m);
    float sum = ex;
    sum += __shfl_xor(sum, 1, 64);
    sum += __shfl_xor(sum, 2, 64);
    sum += __shfl_xor(sum, 4, 64);
    sum += __shfl_xor(sum, 8, 64);
    float r = v - m - logf(sum);

    if (k == 0) out[(size_t)i * NC + f] = r;
}

// ================= launch =================

extern "C" void kernel_launch(void* const* d_in, const int* in_sizes, int n_in,
                              void* d_out, int out_size, void* d_ws, size_t ws_size,
                              hipStream_t stream) {
    const float* x  = (const float*)d_in[0];
    const int*   ei = (const int*)d_in[1];
    const float* W1 = (const float*)d_in[2];
    const float* b1 = (const float*)d_in[3];
    const float* W2 = (const float*)d_in[4];
    const float* b2 = (const float*)d_in[5];
    float* out = (float*)d_out;

    const int N = in_sizes[0] / FIN;        // 50000
    const int E = in_sizes[1] / 2;          // 1600000
    const int* row = ei;                    // targets
    const int* col = ei + E;                // sources
    const int NB = (N + 255) >> 8;          // 196 buckets (<=256)

    // ---- workspace layout ----
    char* w = (char*)d_ws;
    int*   cnt    = (int*)w;                w += (size_t)N * 4;
    int*   off    = (int*)w;                w += (size_t)N * 4;
    int*   cur    = (int*)w;                w += (size_t)N * 4;
    int*   offtmp = (int*)w;                w += (size_t)N * 4;
    int*   bsum   = (int*)w;                w += 256 * 4;
    int*   bcur   = (int*)w;                w += 256 * 4;
    int*   colS   = (int*)w;                w += (size_t)E * 4;
    float* dinv   = (float*)w;              w += (size_t)N * 4;
    float* h1     = (float*)w;              w += (size_t)N * HID * 4;
    float* agg1   = (float*)w;              w += (size_t)N * HID * 4;
    float* h2     = (float*)w;              w += (size_t)N * NC * 4;
    // stage (E int2 = 12.8MB) overlays h1+agg1 (25.6MB): dead before k_gemm1 writes h1
    int2*  stage  = (int2*)h1;

    const int B = 256;
    const int nbN = (N + B - 1) / B;   // 196

    hipMemsetAsync(cnt, 0, (size_t)N * 4, stream);
    k_hist<<<(E + B - 1) / B, B, 0, stream>>>(row, cnt, E);

    k_scan_block<<<nbN, B, 0, stream>>>(cnt, offtmp, bsum, N);
    k_scan_bsum<<<1, B, 0, stream>>>(bsum, nbN);
    k_off<<<nbN, B, 0, stream>>>(offtmp, bsum, cnt, off, cur, dinv, N);
    k_bstart<<<1, B, 0, stream>>>(off, bcur, NB);

    k_bin<<<(E + BIN_CHUNK - 1) / BIN_CHUNK, B, 0, stream>>>(row, col, bcur, stage, E);
    k_place<<<(E + B - 1) / B, B, 0, stream>>>(stage, cur, colS, E);

    k_gemm1<<<(N + G1_ROWS - 1) / G1_ROWS, B, 0, stream>>>(x, W1, h1, N);
    k_agg1<<<(N + 3) / 4, B, 0, stream>>>(off, cnt, colS, dinv, h1, agg1, N);

    k_gemm2<<<N / 16, B, 0, stream>>>(agg1, b1, W2, h2);
    k_agg2f<<<(N + 3) / 4, B, 0, stream>>>(off, cnt, colS, dinv, h2, b2, out, N);
}

// Round 18
// 383.374 us; speedup vs baseline: 1.0862x; 1.0862x over previous
//
#include <hip/hip_runtime.h>
#include <math.h>

#define FIN 256
#define HID 64
#define NC  16

// ================= histogram =================

__global__ void k_hist(const int* __restrict__ row, int* __restrict__ cnt, int E) {
    int e = blockIdx.x * blockDim.x + threadIdx.x;
    if (e < E) atomicAdd(&cnt[row[e]], 1);
}

// ================= exclusive scan of cnt -> off (2-level) =================

__global__ void k_scan_block(const int* __restrict__ cnt, int* __restrict__ offtmp,
                             int* __restrict__ bsum, int N) {
    __shared__ int s[256];
    int t = threadIdx.x, i = blockIdx.x * 256 + t;
    int v = (i < N) ? cnt[i] : 0;
    s[t] = v; __syncthreads();
    for (int d = 1; d < 256; d <<= 1) {
        int add = (t >= d) ? s[t - d] : 0;
        __syncthreads();
        s[t] += add;
        __syncthreads();
    }
    if (i < N) offtmp[i] = s[t] - v;
    if (t == 255) bsum[blockIdx.x] = s[255];
}

__global__ void k_scan_bsum(int* __restrict__ bsum, int nb) {
    __shared__ int s[256];
    int t = threadIdx.x;
    int v = (t < nb) ? bsum[t] : 0;
    s[t] = v; __syncthreads();
    for (int d = 1; d < 256; d <<= 1) {
        int add = (t >= d) ? s[t - d] : 0;
        __syncthreads();
        s[t] += add;
        __syncthreads();
    }
    if (t < nb) bsum[t] = s[t] - v;
}

// off/cur from scan, dinv from cnt (fused, one pass over nodes)
__global__ void k_off(const int* __restrict__ offtmp, const int* __restrict__ bsum,
                      const int* __restrict__ cnt, int* __restrict__ off,
                      int* __restrict__ cur, float* __restrict__ dinv, int N) {
    int i = blockIdx.x * blockDim.x + threadIdx.x;
    if (i < N) {
        int o = offtmp[i] + bsum[i >> 8];
        off[i] = o;
        cur[i] = o;
        dinv[i] = rsqrtf((float)(cnt[i] + 1));   // +1 self loop
    }
}

// bucket start cursors: bucket b covers nodes [b*256, (b+1)*256)
__global__ void k_bstart(const int* __restrict__ off, int* __restrict__ bcur, int NB) {
    int b = threadIdx.x;
    if (b < NB) bcur[b] = off[b << 8];
}

// ================= pass 1: bin edges by bucket into stage =================

#define BIN_CHUNK 4096   // 256 threads x 16 edges

__global__ __launch_bounds__(256) void k_bin(const int* __restrict__ row,
                                             const int* __restrict__ col,
                                             int* __restrict__ bcur,
                                             int2* __restrict__ stage, int E) {
    __shared__ unsigned lcnt[256];
    __shared__ unsigned lpos[256];
    const int tid = threadIdx.x;
    const int base = blockIdx.x * BIN_CHUNK;

    lcnt[tid] = 0;
    __syncthreads();

    int      rr[16];
    unsigned myofs[16];
#pragma unroll
    for (int k = 0; k < 16; ++k) {
        int idx = base + tid + k * 256;
        if (idx < E) {
            int r = row[idx];
            rr[k] = r;
            myofs[k] = atomicAdd(&lcnt[r >> 8], 1u);
        }
    }
    __syncthreads();

    unsigned c = lcnt[tid];
    lpos[tid] = (c > 0) ? (unsigned)atomicAdd(&bcur[tid], (int)c) : 0u;
    __syncthreads();

#pragma unroll
    for (int k = 0; k < 16; ++k) {
        int idx = base + tid + k * 256;
        if (idx < E) {
            int r = rr[k];
            unsigned p = lpos[r >> 8] + myofs[k];
            stage[p] = make_int2(r, col[idx]);
        }
    }
}

// ================= pass 2: place staged edges (bucket-localized) =================

__global__ void k_place(const int2* __restrict__ stage, int* __restrict__ cur,
                        int* __restrict__ colS, int E) {
    int e = blockIdx.x * blockDim.x + threadIdx.x;
    if (e < E) {
        int2 rc = stage[e];
        int p = atomicAdd(&cur[rc.x], 1);
        colS[p] = rc.y;
    }
}

// ================= GEMM1: h1 = x @ W1, 64-row tile, K tiled by 64 =================
// LDS = xs 17.4KB + Ws 16KB = 33.4KB -> 4 blocks/CU; launch_bounds(256,4) caps
// VGPR at 128 -> 4 waves/SIMD. TLP now covers LDS latency (R15 failed at 1 wave/SIMD).

#define G1_ROWS 64
#define G1_KT   64

__global__ __launch_bounds__(256, 4) void k_gemm1(const float* __restrict__ x,
                                                  const float* __restrict__ W1,
                                                  float* __restrict__ h1, int N) {
    __shared__ float xs[G1_ROWS][G1_KT + 4];  // 17.4 KB, padded
    __shared__ float Ws[G1_KT][HID];          // 16 KB
    const int tid = threadIdx.x;
    const int row0 = blockIdx.x * G1_ROWS;

    const int rg = (tid >> 4) << 2;           // row-group base: 0..60
    const int c0 = (tid & 15) << 2;           // col base: 0..60
    float acc[4][4] = {};

    for (int kt = 0; kt < FIN; kt += G1_KT) {
        // load W panel [64][64]: 1024 float4, 4 per thread (16 float4 per row)
#pragma unroll
        for (int i = 0; i < 4; ++i) {
            int idx = tid + i * 256;
            int kr = idx >> 4;
            int q  = idx & 15;
            ((float4*)&Ws[kr][0])[q] =
                ((const float4*)(W1 + (size_t)(kt + kr) * HID))[q];
        }
        // load x tile [64][64]: 1024 float4, 4 per thread (row-guarded)
#pragma unroll
        for (int i = 0; i < 4; ++i) {
            int idx = tid + i * 256;
            int r = idx >> 4;
            int q = idx & 15;
            int gr = row0 + r;
            float4 v = make_float4(0.f, 0.f, 0.f, 0.f);
            if (gr < N) v = ((const float4*)(x + (size_t)gr * FIN + kt))[q];
            *(float4*)&xs[r][q * 4] = v;
        }
        __syncthreads();

#pragma unroll 4
        for (int k = 0; k < G1_KT; k += 4) {
            float4 w0 = *(const float4*)&Ws[k + 0][c0];
            float4 w1 = *(const float4*)&Ws[k + 1][c0];
            float4 w2 = *(const float4*)&Ws[k + 2][c0];
            float4 w3 = *(const float4*)&Ws[k + 3][c0];
            float4 xv0 = *(const float4*)&xs[rg + 0][k];
            float4 xv1 = *(const float4*)&xs[rg + 1][k];
            float4 xv2 = *(const float4*)&xs[rg + 2][k];
            float4 xv3 = *(const float4*)&xs[rg + 3][k];
#define G1_ROW(i, xv)                                                        \
            acc[i][0] += xv.x * w0.x + xv.y * w1.x + xv.z * w2.x + xv.w * w3.x; \
            acc[i][1] += xv.x * w0.y + xv.y * w1.y + xv.z * w2.y + xv.w * w3.y; \
            acc[i][2] += xv.x * w0.z + xv.y * w1.z + xv.z * w2.z + xv.w * w3.z; \
            acc[i][3] += xv.x * w0.w + xv.y * w1.w + xv.z * w2.w + xv.w * w3.w;
            G1_ROW(0, xv0) G1_ROW(1, xv1) G1_ROW(2, xv2) G1_ROW(3, xv3)
#undef G1_ROW
        }
        __syncthreads();
    }

#pragma unroll
    for (int i = 0; i < 4; ++i) {
        int gr = row0 + rg + i;
        if (gr < N) {
            float4 v = make_float4(acc[i][0], acc[i][1], acc[i][2], acc[i][3]);
            *(float4*)(h1 + (size_t)gr * HID + c0) = v;
        }
    }
}

// ================= agg1: gather-reduce, wave per node, lane = feature =================

__global__ __launch_bounds__(256) void k_agg1(const int* __restrict__ off,
                                              const int* __restrict__ cnt,
                                              const int* __restrict__ colS,
                                              const float* __restrict__ dinv,
                                              const float* __restrict__ h1,
                                              float* __restrict__ agg1, int N) {
    int i = blockIdx.x * 4 + (threadIdx.x >> 6);
    if (i >= N) return;
    int lane = threadIdx.x & 63;
    int s = off[i], n = cnt[i];
    float di = dinv[i];
    float acc = di * h1[(size_t)i * HID + lane];   // self loop (pre-factored)

    int j = 0;
    for (; j + 4 <= n; j += 4) {
        int   c0 = colS[s + j],     c1 = colS[s + j + 1];
        int   c2 = colS[s + j + 2], c3 = colS[s + j + 3];
        float w0 = dinv[c0], w1 = dinv[c1], w2 = dinv[c2], w3 = dinv[c3];
        acc += h1[(size_t)c0 * HID + lane] * w0;
        acc += h1[(size_t)c1 * HID + lane] * w1;
        acc += h1[(size_t)c2 * HID + lane] * w2;
        acc += h1[(size_t)c3 * HID + lane] * w3;
    }
    for (; j < n; ++j) {
        int c = colS[s + j];
        acc += h1[(size_t)c * HID + lane] * dinv[c];
    }
    agg1[(size_t)i * HID + lane] = di * acc;
}

// ================= GEMM2 fused: h2 = relu(agg1 + b1) @ W2 =================

__global__ __launch_bounds__(256) void k_gemm2(const float* __restrict__ agg1,
                                               const float* __restrict__ b1,
                                               const float* __restrict__ W2,
                                               float* __restrict__ h2) {
    __shared__ float Ws[HID * NC];
    __shared__ float hs[16][HID + 4];
    const int tid = threadIdx.x;

#pragma unroll
    for (int i = 0; i < 4; ++i) Ws[tid + i * 256] = W2[tid + i * 256];

    const int n0 = blockIdx.x * 16;
    {
        float4 v = ((const float4*)(agg1 + (size_t)n0 * HID))[tid];
        int n  = tid >> 4;
        int k0 = (tid & 15) << 2;
        float4 bb = *(const float4*)(b1 + k0);
        v.x = fmaxf(v.x + bb.x, 0.f);
        v.y = fmaxf(v.y + bb.y, 0.f);
        v.z = fmaxf(v.z + bb.z, 0.f);
        v.w = fmaxf(v.w + bb.w, 0.f);
        *(float4*)&hs[n][k0] = v;
    }
    __syncthreads();

    const int n = tid >> 4;
    const int c = tid & 15;
    float acc = 0.f;
#pragma unroll
    for (int k = 0; k < HID; ++k) {
        acc += hs[n][k] * Ws[k * NC + c];
    }
    h2[(size_t)(n0 + n) * NC + c] = acc;
}

// ================= agg2 + bias + log_softmax fused =================
// wave per node: f = lane&15, phase = lane>>4; phase-reduce, then 16-lane softmax.

__global__ __launch_bounds__(256) void k_agg2f(const int* __restrict__ off,
                                               const int* __restrict__ cnt,
                                               const int* __restrict__ colS,
                                               const float* __restrict__ dinv,
                                               const float* __restrict__ h2,
                                               const float* __restrict__ b2,
                                               float* __restrict__ out, int N) {
    int i = blockIdx.x * 4 + (threadIdx.x >> 6);
    if (i >= N) return;
    int lane = threadIdx.x & 63;
    int f = lane & 15;
    int k = lane >> 4;
    int s = off[i], n = cnt[i];

    float acc = 0.f;
    for (int j = k; j < n; j += 4) {
        int c = colS[s + j];
        acc += h2[(size_t)c * NC + f] * dinv[c];
    }
    acc += __shfl_xor(acc, 16, 64);
    acc += __shfl_xor(acc, 32, 64);           // every lane now has S_f for its f

    float di = dinv[i];
    float v = di * (acc + di * h2[(size_t)i * NC + f]) + b2[f];

    // 16-lane softmax reduce (masks 1,2,4,8 stay within each 16-lane group)
    float m = v;
    m = fmaxf(m, __shfl_xor(m, 1, 64));
    m = fmaxf(m, __shfl_xor(m, 2, 64));
    m = fmaxf(m, __shfl_xor(m, 4, 64));
    m = fmaxf(m, __shfl_xor(m, 8, 64));
    float ex = expf(v - m);
    float sum = ex;
    sum += __shfl_xor(sum, 1, 64);
    sum += __shfl_xor(sum, 2, 64);
    sum += __shfl_xor(sum, 4, 64);
    sum += __shfl_xor(sum, 8, 64);
    float r = v - m - logf(sum);

    if (k == 0) out[(size_t)i * NC + f] = r;
}

// ================= launch =================

extern "C" void kernel_launch(void* const* d_in, const int* in_sizes, int n_in,
                              void* d_out, int out_size, void* d_ws, size_t ws_size,
                              hipStream_t stream) {
    const float* x  = (const float*)d_in[0];
    const int*   ei = (const int*)d_in[1];
    const float* W1 = (const float*)d_in[2];
    const float* b1 = (const float*)d_in[3];
    const float* W2 = (const float*)d_in[4];
    const float* b2 = (const float*)d_in[5];
    float* out = (float*)d_out;

    const int N = in_sizes[0] / FIN;        // 50000
    const int E = in_sizes[1] / 2;          // 1600000
    const int* row = ei;                    // targets
    const int* col = ei + E;                // sources
    const int NB = (N + 255) >> 8;          // 196 buckets (<=256)

    // ---- workspace layout ----
    char* w = (char*)d_ws;
    int*   cnt    = (int*)w;                w += (size_t)N * 4;
    int*   off    = (int*)w;                w += (size_t)N * 4;
    int*   cur    = (int*)w;                w += (size_t)N * 4;
    int*   offtmp = (int*)w;                w += (size_t)N * 4;
    int*   bsum   = (int*)w;                w += 256 * 4;
    int*   bcur   = (int*)w;                w += 256 * 4;
    int*   colS   = (int*)w;                w += (size_t)E * 4;
    float* dinv   = (float*)w;              w += (size_t)N * 4;
    float* h1     = (float*)w;              w += (size_t)N * HID * 4;
    float* agg1   = (float*)w;              w += (size_t)N * HID * 4;
    float* h2     = (float*)w;              w += (size_t)N * NC * 4;
    // stage (E int2 = 12.8MB) overlays h1+agg1 (25.6MB): dead before k_gemm1 writes h1
    int2*  stage  = (int2*)h1;

    const int B = 256;
    const int nbN = (N + B - 1) / B;   // 196

    hipMemsetAsync(cnt, 0, (size_t)N * 4, stream);
    k_hist<<<(E + B - 1) / B, B, 0, stream>>>(row, cnt, E);

    k_scan_block<<<nbN, B, 0, stream>>>(cnt, offtmp, bsum, N);
    k_scan_bsum<<<1, B, 0, stream>>>(bsum, nbN);
    k_off<<<nbN, B, 0, stream>>>(offtmp, bsum, cnt, off, cur, dinv, N);
    k_bstart<<<1, B, 0, stream>>>(off, bcur, NB);

    k_bin<<<(E + BIN_CHUNK - 1) / BIN_CHUNK, B, 0, stream>>>(row, col, bcur, stage, E);
    k_place<<<(E + B - 1) / B, B, 0, stream>>>(stage, cur, colS, E);

    k_gemm1<<<(N + G1_ROWS - 1) / G1_ROWS, B, 0, stream>>>(x, W1, h1, N);
    k_agg1<<<(N + 3) / 4, B, 0, stream>>>(off, cnt, colS, dinv, h1, agg1, N);

    k_gemm2<<<N / 16, B, 0, stream>>>(agg1, b1, W2, h2);
    k_agg2f<<<(N + 3) / 4, B, 0, stream>>>(off, cnt, colS, dinv, h2, b2, out, N);
}

// Round 19
// 371.298 us; speedup vs baseline: 1.1216x; 1.0325x over previous
//
#include <hip/hip_runtime.h>
#include <math.h>

#define FIN 256
#define HID 64
#define NC  16

// ================= histogram =================

__global__ void k_hist(const int* __restrict__ row, int* __restrict__ cnt, int E) {
    int e = blockIdx.x * blockDim.x + threadIdx.x;
    if (e < E) atomicAdd(&cnt[row[e]], 1);
}

// ================= exclusive scan of cnt -> off (2-level) =================

__global__ void k_scan_block(const int* __restrict__ cnt, int* __restrict__ offtmp,
                             int* __restrict__ bsum, int N) {
    __shared__ int s[256];
    int t = threadIdx.x, i = blockIdx.x * 256 + t;
    int v = (i < N) ? cnt[i] : 0;
    s[t] = v; __syncthreads();
    for (int d = 1; d < 256; d <<= 1) {
        int add = (t >= d) ? s[t - d] : 0;
        __syncthreads();
        s[t] += add;
        __syncthreads();
    }
    if (i < N) offtmp[i] = s[t] - v;
    if (t == 255) bsum[blockIdx.x] = s[255];
}

__global__ void k_scan_bsum(int* __restrict__ bsum, int nb) {
    __shared__ int s[256];
    int t = threadIdx.x;
    int v = (t < nb) ? bsum[t] : 0;
    s[t] = v; __syncthreads();
    for (int d = 1; d < 256; d <<= 1) {
        int add = (t >= d) ? s[t - d] : 0;
        __syncthreads();
        s[t] += add;
        __syncthreads();
    }
    if (t < nb) bsum[t] = s[t] - v;
}

// off/cur from scan, dinv from cnt (fused, one pass over nodes)
__global__ void k_off(const int* __restrict__ offtmp, const int* __restrict__ bsum,
                      const int* __restrict__ cnt, int* __restrict__ off,
                      int* __restrict__ cur, float* __restrict__ dinv, int N) {
    int i = blockIdx.x * blockDim.x + threadIdx.x;
    if (i < N) {
        int o = offtmp[i] + bsum[i >> 8];
        off[i] = o;
        cur[i] = o;
        dinv[i] = rsqrtf((float)(cnt[i] + 1));   // +1 self loop
    }
}

// bucket start cursors: bucket b covers nodes [b*256, (b+1)*256)
__global__ void k_bstart(const int* __restrict__ off, int* __restrict__ bcur, int NB) {
    int b = threadIdx.x;
    if (b < NB) bcur[b] = off[b << 8];
}

// ================= pass 1: bin edges by bucket into stage =================

#define BIN_CHUNK 4096   // 256 threads x 16 edges

__global__ __launch_bounds__(256) void k_bin(const int* __restrict__ row,
                                             const int* __restrict__ col,
                                             int* __restrict__ bcur,
                                             int2* __restrict__ stage, int E) {
    __shared__ unsigned lcnt[256];
    __shared__ unsigned lpos[256];
    const int tid = threadIdx.x;
    const int base = blockIdx.x * BIN_CHUNK;

    lcnt[tid] = 0;
    __syncthreads();

    int      rr[16];
    unsigned myofs[16];
#pragma unroll
    for (int k = 0; k < 16; ++k) {
        int idx = base + tid + k * 256;
        if (idx < E) {
            int r = row[idx];
            rr[k] = r;
            myofs[k] = atomicAdd(&lcnt[r >> 8], 1u);
        }
    }
    __syncthreads();

    unsigned c = lcnt[tid];
    lpos[tid] = (c > 0) ? (unsigned)atomicAdd(&bcur[tid], (int)c) : 0u;
    __syncthreads();

#pragma unroll
    for (int k = 0; k < 16; ++k) {
        int idx = base + tid + k * 256;
        if (idx < E) {
            int r = rr[k];
            unsigned p = lpos[r >> 8] + myofs[k];
            stage[p] = make_int2(r, col[idx]);
        }
    }
}

// ================= pass 2: place staged edges (bucket-localized) =================

__global__ void k_place(const int2* __restrict__ stage, int* __restrict__ cur,
                        int* __restrict__ colS, int E) {
    int e = blockIdx.x * blockDim.x + threadIdx.x;
    if (e < E) {
        int2 rc = stage[e];
        int p = atomicAdd(&cur[rc.x], 1);
        colS[p] = rc.y;
    }
}

// ================= GEMM1: h1 = x @ W1, 64-row tile, K tiled by 64 =================

#define G1_ROWS 64
#define G1_KT   64

__global__ __launch_bounds__(256, 4) void k_gemm1(const float* __restrict__ x,
                                                  const float* __restrict__ W1,
                                                  float* __restrict__ h1, int N) {
    __shared__ float xs[G1_ROWS][G1_KT + 4];  // 17.4 KB, padded
    __shared__ float Ws[G1_KT][HID];          // 16 KB
    const int tid = threadIdx.x;
    const int row0 = blockIdx.x * G1_ROWS;

    const int rg = (tid >> 4) << 2;           // row-group base: 0..60
    const int c0 = (tid & 15) << 2;           // col base: 0..60
    float acc[4][4] = {};

    for (int kt = 0; kt < FIN; kt += G1_KT) {
        // load W panel [64][64]: 1024 float4, 4 per thread
#pragma unroll
        for (int i = 0; i < 4; ++i) {
            int idx = tid + i * 256;
            int kr = idx >> 4;
            int q  = idx & 15;
            ((float4*)&Ws[kr][0])[q] =
                ((const float4*)(W1 + (size_t)(kt + kr) * HID))[q];
        }
        // load x tile [64][64]: 1024 float4, 4 per thread (row-guarded)
#pragma unroll
        for (int i = 0; i < 4; ++i) {
            int idx = tid + i * 256;
            int r = idx >> 4;
            int q = idx & 15;
            int gr = row0 + r;
            float4 v = make_float4(0.f, 0.f, 0.f, 0.f);
            if (gr < N) v = ((const float4*)(x + (size_t)gr * FIN + kt))[q];
            *(float4*)&xs[r][q * 4] = v;
        }
        __syncthreads();

#pragma unroll 4
        for (int k = 0; k < G1_KT; k += 4) {
            float4 w0 = *(const float4*)&Ws[k + 0][c0];
            float4 w1 = *(const float4*)&Ws[k + 1][c0];
            float4 w2 = *(const float4*)&Ws[k + 2][c0];
            float4 w3 = *(const float4*)&Ws[k + 3][c0];
            float4 xv0 = *(const float4*)&xs[rg + 0][k];
            float4 xv1 = *(const float4*)&xs[rg + 1][k];
            float4 xv2 = *(const float4*)&xs[rg + 2][k];
            float4 xv3 = *(const float4*)&xs[rg + 3][k];
#define G1_ROW(i, xv)                                                        \
            acc[i][0] += xv.x * w0.x + xv.y * w1.x + xv.z * w2.x + xv.w * w3.x; \
            acc[i][1] += xv.x * w0.y + xv.y * w1.y + xv.z * w2.y + xv.w * w3.y; \
            acc[i][2] += xv.x * w0.z + xv.y * w1.z + xv.z * w2.z + xv.w * w3.z; \
            acc[i][3] += xv.x * w0.w + xv.y * w1.w + xv.z * w2.w + xv.w * w3.w;
            G1_ROW(0, xv0) G1_ROW(1, xv1) G1_ROW(2, xv2) G1_ROW(3, xv3)
#undef G1_ROW
        }
        __syncthreads();
    }

#pragma unroll
    for (int i = 0; i < 4; ++i) {
        int gr = row0 + rg + i;
        if (gr < N) {
            float4 v = make_float4(acc[i][0], acc[i][1], acc[i][2], acc[i][3]);
            *(float4*)(h1 + (size_t)gr * HID + c0) = v;
        }
    }
}

// ================= agg1: gather-reduce, wave per node, lane = feature =================
// 8 gathers in flight (R18 profile: latency-bound — 42% BW, 28% VALU, 69% occ).

__global__ __launch_bounds__(256) void k_agg1(const int* __restrict__ off,
                                              const int* __restrict__ cnt,
                                              const int* __restrict__ colS,
                                              const float* __restrict__ dinv,
                                              const float* __restrict__ h1,
                                              float* __restrict__ agg1, int N) {
    int i = blockIdx.x * 4 + (threadIdx.x >> 6);
    if (i >= N) return;
    int lane = threadIdx.x & 63;
    int s = off[i], n = cnt[i];
    float di = dinv[i];
    float acc = di * h1[(size_t)i * HID + lane];   // self loop (pre-factored)

    int j = 0;
    for (; j + 8 <= n; j += 8) {
        int cc[8];
#pragma unroll
        for (int u = 0; u < 8; ++u) cc[u] = colS[s + j + u];
        float ww[8];
#pragma unroll
        for (int u = 0; u < 8; ++u) ww[u] = dinv[cc[u]];
        float hv[8];
#pragma unroll
        for (int u = 0; u < 8; ++u) hv[u] = h1[(size_t)cc[u] * HID + lane];
#pragma unroll
        for (int u = 0; u < 8; ++u) acc += hv[u] * ww[u];
    }
    for (; j + 4 <= n; j += 4) {
        int   c0 = colS[s + j],     c1 = colS[s + j + 1];
        int   c2 = colS[s + j + 2], c3 = colS[s + j + 3];
        float w0 = dinv[c0], w1 = dinv[c1], w2 = dinv[c2], w3 = dinv[c3];
        acc += h1[(size_t)c0 * HID + lane] * w0;
        acc += h1[(size_t)c1 * HID + lane] * w1;
        acc += h1[(size_t)c2 * HID + lane] * w2;
        acc += h1[(size_t)c3 * HID + lane] * w3;
    }
    for (; j < n; ++j) {
        int c = colS[s + j];
        acc += h1[(size_t)c * HID + lane] * dinv[c];
    }
    agg1[(size_t)i * HID + lane] = di * acc;
}

// ================= GEMM2 fused: h2 = relu(agg1 + b1) @ W2 =================

__global__ __launch_bounds__(256) void k_gemm2(const float* __restrict__ agg1,
                                               const float* __restrict__ b1,
                                               const float* __restrict__ W2,
                                               float* __restrict__ h2) {
    __shared__ float Ws[HID * NC];
    __shared__ float hs[16][HID + 4];
    const int tid = threadIdx.x;

#pragma unroll
    for (int i = 0; i < 4; ++i) Ws[tid + i * 256] = W2[tid + i * 256];

    const int n0 = blockIdx.x * 16;
    {
        float4 v = ((const float4*)(agg1 + (size_t)n0 * HID))[tid];
        int n  = tid >> 4;
        int k0 = (tid & 15) << 2;
        float4 bb = *(const float4*)(b1 + k0);
        v.x = fmaxf(v.x + bb.x, 0.f);
        v.y = fmaxf(v.y + bb.y, 0.f);
        v.z = fmaxf(v.z + bb.z, 0.f);
        v.w = fmaxf(v.w + bb.w, 0.f);
        *(float4*)&hs[n][k0] = v;
    }
    __syncthreads();

    const int n = tid >> 4;
    const int c = tid & 15;
    float acc = 0.f;
#pragma unroll
    for (int k = 0; k < HID; ++k) {
        acc += hs[n][k] * Ws[k * NC + c];
    }
    h2[(size_t)(n0 + n) * NC + c] = acc;
}

// ================= agg2 + bias + log_softmax fused =================
// wave per node: f = lane&15, phase = lane>>4; 2 edges per phase in flight.

__global__ __launch_bounds__(256) void k_agg2f(const int* __restrict__ off,
                                               const int* __restrict__ cnt,
                                               const int* __restrict__ colS,
                                               const float* __restrict__ dinv,
                                               const float* __restrict__ h2,
                                               const float* __restrict__ b2,
                                               float* __restrict__ out, int N) {
    int i = blockIdx.x * 4 + (threadIdx.x >> 6);
    if (i >= N) return;
    int lane = threadIdx.x & 63;
    int f = lane & 15;
    int k = lane >> 4;
    int s = off[i], n = cnt[i];

    float acc = 0.f;
    int j = k;
    for (; j + 4 < n; j += 8) {
        int c0 = colS[s + j];
        int c1 = colS[s + j + 4];
        float w0 = dinv[c0], w1 = dinv[c1];
        float v0 = h2[(size_t)c0 * NC + f];
        float v1 = h2[(size_t)c1 * NC + f];
        acc += v0 * w0 + v1 * w1;
    }
    for (; j < n; j += 4) {
        int c = colS[s + j];
        acc += h2[(size_t)c * NC + f] * dinv[c];
    }
    acc += __shfl_xor(acc, 16, 64);
    acc += __shfl_xor(acc, 32, 64);           // every lane now has S_f for its f

    float di = dinv[i];
    float v = di * (acc + di * h2[(size_t)i * NC + f]) + b2[f];

    // 16-lane softmax reduce (masks 1,2,4,8 stay within each 16-lane group)
    float m = v;
    m = fmaxf(m, __shfl_xor(m, 1, 64));
    m = fmaxf(m, __shfl_xor(m, 2, 64));
    m = fmaxf(m, __shfl_xor(m, 4, 64));
    m = fmaxf(m, __shfl_xor(m, 8, 64));
    float ex = expf(v - m);
    float sum = ex;
    sum += __shfl_xor(sum, 1, 64);
    sum += __shfl_xor(sum, 2, 64);
    sum += __shfl_xor(sum, 4, 64);
    sum += __shfl_xor(sum, 8, 64);
    float r = v - m - logf(sum);

    if (k == 0) out[(size_t)i * NC + f] = r;
}

// ================= launch =================

extern "C" void kernel_launch(void* const* d_in, const int* in_sizes, int n_in,
                              void* d_out, int out_size, void* d_ws, size_t ws_size,
                              hipStream_t stream) {
    const float* x  = (const float*)d_in[0];
    const int*   ei = (const int*)d_in[1];
    const float* W1 = (const float*)d_in[2];
    const float* b1 = (const float*)d_in[3];
    const float* W2 = (const float*)d_in[4];
    const float* b2 = (const float*)d_in[5];
    float* out = (float*)d_out;

    const int N = in_sizes[0] / FIN;        // 50000
    const int E = in_sizes[1] / 2;          // 1600000
    const int* row = ei;                    // targets
    const int* col = ei + E;                // sources
    const int NB = (N + 255) >> 8;          // 196 buckets (<=256)

    // ---- workspace layout ----
    char* w = (char*)d_ws;
    int*   cnt    = (int*)w;                w += (size_t)N * 4;
    int*   off    = (int*)w;                w += (size_t)N * 4;
    int*   cur    = (int*)w;                w += (size_t)N * 4;
    int*   offtmp = (int*)w;                w += (size_t)N * 4;
    int*   bsum   = (int*)w;                w += 256 * 4;
    int*   bcur   = (int*)w;                w += 256 * 4;
    int*   colS   = (int*)w;                w += (size_t)E * 4;
    float* dinv   = (float*)w;              w += (size_t)N * 4;
    float* h1     = (float*)w;              w += (size_t)N * HID * 4;
    float* agg1   = (float*)w;              w += (size_t)N * HID * 4;
    float* h2     = (float*)w;              w += (size_t)N * NC * 4;
    // stage (E int2 = 12.8MB) overlays h1+agg1 (25.6MB): dead before k_gemm1 writes h1
    int2*  stage  = (int2*)h1;

    const int B = 256;
    const int nbN = (N + B - 1) / B;   // 196

    hipMemsetAsync(cnt, 0, (size_t)N * 4, stream);
    k_hist<<<(E + B - 1) / B, B, 0, stream>>>(row, cnt, E);

    k_scan_block<<<nbN, B, 0, stream>>>(cnt, offtmp, bsum, N);
    k_scan_bsum<<<1, B, 0, stream>>>(bsum, nbN);
    k_off<<<nbN, B, 0, stream>>>(offtmp, bsum, cnt, off, cur, dinv, N);
    k_bstart<<<1, B, 0, stream>>>(off, bcur, NB);

    k_bin<<<(E + BIN_CHUNK - 1) / BIN_CHUNK, B, 0, stream>>>(row, col, bcur, stage, E);
    k_place<<<(E + B - 1) / B, B, 0, stream>>>(stage, cur, colS, E);

    k_gemm1<<<(N + G1_ROWS - 1) / G1_ROWS, B, 0, stream>>>(x, W1, h1, N);
    k_agg1<<<(N + 3) / 4, B, 0, stream>>>(off, cnt, colS, dinv, h1, agg1, N);

    k_gemm2<<<N / 16, B, 0, stream>>>(agg1, b1, W2, h2);
    k_agg2f<<<(N + 3) / 4, B, 0, stream>>>(off, cnt, colS, dinv, h2, b2, out, N);
}